// Round 4
// baseline (1258.117 us; speedup 1.0000x reference)
//
#include <hip/hip_runtime.h>

// TsRnn round 4: distributed LSTM2 + LDS-staged input.
//  - LSTM2 dot computed as per-thread register partials (c1 never leaves regs),
//    reduced via shfl_xor + LDS atomicAdd into a 64-float plane (4-plane
//    rotation, zeroed 2 barriers ahead of reuse); every wave redundantly
//    finishes LSTM2 -> no serial wave-7 tail, ONE barrier per step everywhere.
//  - Input staged into LDS in 32-step double-buffered chunks: no per-step HBM
//    load, no vmcnt drain at the barrier.
//  - h planes zero-initialized (B-build reads k=100..127 tail).
//  - Tile balance {4,3,3,3,3,3,3,3}.

#define TT      512
#define BATCH   4096
#define CELLN   100
#define FUTS    64
#define THREADS 512
#define BPB     16
#define HPITCH  136   // bf16 elems per h-plane row (272 B, 16B-aligned rows)
#define XCH     32    // x-stage chunk (steps)
#define XPITCH  20    // padded floats per x-stage row
#define LOG2E   1.4426950408889634f

typedef __attribute__((ext_vector_type(8))) short bf16x8;
typedef __attribute__((ext_vector_type(4))) float f32x4;

__device__ __forceinline__ unsigned short f2bf(float f) {
  unsigned u = __builtin_bit_cast(unsigned, f);
  unsigned r = (u + 0x7FFFu + ((u >> 16) & 1u)) >> 16;
  return (unsigned short)r;
}
__device__ __forceinline__ float bf2f(unsigned short b) {
  return __builtin_bit_cast(float, ((unsigned)b) << 16);
}
// s = x*log2e -> sigmoid(x); safe at +-inf
__device__ __forceinline__ float sig_s(float s) {
  return __builtin_amdgcn_rcpf(1.f + __builtin_amdgcn_exp2f(-s));
}
// u = 2*log2e*x -> tanh(x); safe at +-inf
__device__ __forceinline__ float tanh_s(float u) {
  return fmaf(-2.f, __builtin_amdgcn_rcpf(__builtin_amdgcn_exp2f(u) + 1.f), 1.f);
}

template <int NT>
__device__ __forceinline__ void tiles_step(
    const bf16x8 (&Ahi)[4][4], const bf16x8 (&Alo)[4][4],
    const bf16x8 (&Bhi)[4], const bf16x8 (&Blo)[4],
    const float (&bias_r)[4][4], const float (&wx_r)[4][4],
    const float (&w2r)[4][4],
    float (&c1)[4], float (&pg)[4], float xreg, int mstart, int lane,
    unsigned short (*h_hi)[HPITCH], unsigned short (*h_lo)[HPITCH])
{
  f32x4 accA[NT], accB[NT];
  #pragma unroll
  for (int i = 0; i < NT; ++i) {
    #pragma unroll
    for (int r = 0; r < 4; ++r) {
      accA[i][r] = fmaf(wx_r[i][r], xreg, bias_r[i][r]);
      accB[i][r] = 0.f;
    }
  }
  #pragma unroll
  for (int kk = 0; kk < 4; ++kk)
    #pragma unroll
    for (int i = 0; i < NT; ++i)
      accA[i] = __builtin_amdgcn_mfma_f32_16x16x32_bf16(Ahi[i][kk], Bhi[kk], accA[i], 0, 0, 0);
  #pragma unroll
  for (int kk = 0; kk < 4; ++kk)
    #pragma unroll
    for (int i = 0; i < NT; ++i)
      accB[i] = __builtin_amdgcn_mfma_f32_16x16x32_bf16(Alo[i][kk], Bhi[kk], accB[i], 0, 0, 0);
  #pragma unroll
  for (int kk = 0; kk < 4; ++kk)
    #pragma unroll
    for (int i = 0; i < NT; ++i)
      accB[i] = __builtin_amdgcn_mfma_f32_16x16x32_bf16(Ahi[i][kk], Blo[kk], accB[i], 0, 0, 0);

  const int b = lane & 15;
  #pragma unroll
  for (int i = 0; i < NT; ++i) {
    float si = accA[i][0] + accB[i][0];
    float sf = accA[i][1] + accB[i][1];
    float sg = accA[i][2] + accB[i][2];
    float so = accA[i][3] + accB[i][3];
    float ig = sig_s(si), fg = sig_s(sf), gg = tanh_s(sg), og = sig_s(so);
    float cn = fmaf(fg, c1[i], ig * gg);
    c1[i] = cn;
    float hn = og * tanh_s(2.f * LOG2E * cn);
    const int cc = 4 * (mstart + i) + (lane >> 4);
    unsigned short hh = f2bf(hn);
    h_hi[b][cc] = hh;
    h_lo[b][cc] = f2bf(hn - bf2f(hh));
    // LSTM2 partial dot: this thread's cells only, all 4 gates (scaled W2)
    #pragma unroll
    for (int g = 0; g < 4; ++g) pg[g] = fmaf(w2r[i][g], cn, pg[g]);
  }
}

__global__ __launch_bounds__(THREADS, 2) void lstm_mfma4(
    const float* __restrict__ input,
    const float* __restrict__ W_ih1, const float* __restrict__ W_hh1,
    const float* __restrict__ b_ih1, const float* __restrict__ b_hh1,
    const float* __restrict__ W_ih2, const float* __restrict__ W_hh2,
    const float* __restrict__ b_ih2, const float* __restrict__ b_hh2,
    float* __restrict__ out)
{
  __shared__ __align__(16) unsigned short h_hi[2][BPB][HPITCH];
  __shared__ __align__(16) unsigned short h_lo[2][BPB][HPITCH];
  __shared__ __align__(16) float part[4][BPB][4];     // [plane][batch][gate]
  __shared__ __align__(16) float x_stage[2][XCH][XPITCH];

  const int tid   = threadIdx.x;
  const int lane  = tid & 63;
  const int wv    = tid >> 6;                         // wave 0..7
  const int bbase = blockIdx.x * BPB;
  const int cnt    = (wv == 0) ? 4 : 3;               // 4 + 7*3 = 25 tiles
  const int mstart = (wv == 0) ? 0 : 3 * wv + 1;

  // ---------------- one-time staging ----------------
  bf16x8 Ahi[4][4], Alo[4][4];
  float  bias_r[4][4], wx_r[4][4], w2r[4][4];
  #pragma unroll
  for (int i = 0; i < 4; ++i) {
    #pragma unroll
    for (int kk = 0; kk < 4; ++kk)
      #pragma unroll
      for (int e = 0; e < 8; ++e) { Ahi[i][kk][e] = 0; Alo[i][kk][e] = 0; }
    #pragma unroll
    for (int r = 0; r < 4; ++r) { bias_r[i][r] = 0.f; wx_r[i][r] = 0.f; w2r[i][r] = 0.f; }
    if (i < cnt) {
      const int m  = mstart + i;
      const int R  = 16 * m + (lane & 15);
      const int ce = R >> 2, g = R & 3;
      const float sc = (g == 2) ? 2.f * LOG2E : LOG2E;
      #pragma unroll
      for (int kk = 0; kk < 4; ++kk) {
        #pragma unroll
        for (int e = 0; e < 8; ++e) {
          int k = 32 * kk + (lane >> 4) * 8 + e;
          float v = (k < CELLN) ? W_hh1[(g * CELLN + ce) * CELLN + k] * sc : 0.f;
          unsigned short vh = f2bf(v);
          Ahi[i][kk][e] = (short)vh;
          Alo[i][kk][e] = (short)f2bf(v - bf2f(vh));
        }
      }
      const int cc = 4 * m + (lane >> 4);
      #pragma unroll
      for (int r = 0; r < 4; ++r) {
        const float scr = (r == 2) ? 2.f * LOG2E : LOG2E;
        bias_r[i][r] = (b_ih1[r * CELLN + cc] + b_hh1[r * CELLN + cc]) * scr;
        wx_r[i][r]   = W_ih1[r * CELLN + cc] * scr;
        w2r[i][r]    = W_ih2[r * CELLN + cc] * scr;   // LSTM2 weight for my cell
      }
    }
  }
  float bias2r[4], whh2r[4];
  #pragma unroll
  for (int g = 0; g < 4; ++g) {
    const float scg = (g == 2) ? 2.f * LOG2E : LOG2E;
    bias2r[g] = (b_ih2[g] + b_hh2[g]) * scg;
    whh2r[g]  = W_hh2[g] * scg;
  }

  // zero h planes (B-build reads k tail 100..127) and part planes
  for (int e = tid; e < 2 * BPB * HPITCH; e += THREADS) {
    (&h_hi[0][0][0])[e] = 0; (&h_lo[0][0][0])[e] = 0;
  }
  if (tid < 4 * BPB * 4) (&part[0][0][0])[tid] = 0.f;
  // stage x chunk 0
  x_stage[0][tid >> 4][tid & 15] = input[(size_t)(tid >> 4) * BATCH + bbase + (tid & 15)];

  float c1[4] = {0.f, 0.f, 0.f, 0.f};
  float c2b = 0.f, h2b = 0.f;                 // replicated per-lane (b = lane&15)
  bf16x8 Bhi[4], Blo[4];
  #pragma unroll
  for (int kk = 0; kk < 4; ++kk)
    #pragma unroll
    for (int e = 0; e < 8; ++e) { Bhi[kk][e] = 0; Blo[kk][e] = 0; }

  __syncthreads();
  float xreg = x_stage[0][0][lane & 15];
  float xfut = 0.f;

  // ---------------- time loop: ONE barrier per step ----------------
  for (int t = 0; t < TT + FUTS; ++t) {
    const int p = t & 1;
    // issue next x-chunk load early (HBM latency hidden under 32 steps)
    if ((t & (XCH - 1)) == 0 && t + XCH < TT)
      xfut = input[(size_t)(t + XCH + (tid >> 4)) * BATCH + bbase + (tid & 15)];

    float pg[4] = {0.f, 0.f, 0.f, 0.f};
    if (cnt == 4)
      tiles_step<4>(Ahi, Alo, Bhi, Blo, bias_r, wx_r, w2r, c1, pg, xreg,
                    mstart, lane, h_hi[p], h_lo[p]);
    else
      tiles_step<3>(Ahi, Alo, Bhi, Blo, bias_r, wx_r, w2r, c1, pg, xreg,
                    mstart, lane, h_hi[p], h_lo[p]);

    // in-wave reduce of LSTM2 partials (lanes sharing b = lane&15)
    #pragma unroll
    for (int g = 0; g < 4; ++g) {
      pg[g] += __shfl_xor(pg[g], 16);
      pg[g] += __shfl_xor(pg[g], 32);
    }
    {
      const int q = lane >> 4, b = lane & 15;
      float val = (q == 0) ? pg[0] : (q == 1) ? pg[1] : (q == 2) ? pg[2] : pg[3];
      atomicAdd(&part[t & 3][b][q], val);
    }
    // mid-chunk: commit prefetched x rows to the other stage plane
    if ((t & (XCH - 1)) == 16 && t + 16 < TT)
      x_stage[((t >> 5) + 1) & 1][tid >> 4][tid & 15] = xfut;

    __syncthreads();   // h(t), part(t) published; x-stage writes visible

    // B-build for step t+1 (parity p; publish(t+1) writes p^1)
    {
      const int b    = lane & 15;
      const int koff = (lane >> 4) * 8;
      #pragma unroll
      for (int kk = 0; kk < 4; ++kk)
        Bhi[kk] = *(const bf16x8*)&h_hi[p][b][kk * 32 + koff];
      #pragma unroll
      for (int kk = 0; kk < 4; ++kk)
        Blo[kk] = *(const bf16x8*)&h_lo[p][b][kk * 32 + koff];
    }

    // LSTM2 finish — redundantly on every wave (identical inputs -> identical state)
    {
      const int b = lane & 15;
      f32x4 sv = *(const f32x4*)&part[t & 3][b][0];
      // zero the plane reused at step t+2 (reads of it ended before bar(t-1))
      (&part[(t + 2) & 3][0][0])[lane] = 0.f;
      float s0 = fmaf(whh2r[0], h2b, sv[0] + bias2r[0]);
      float s1 = fmaf(whh2r[1], h2b, sv[1] + bias2r[1]);
      float s2 = fmaf(whh2r[2], h2b, sv[2] + bias2r[2]);
      float s3 = fmaf(whh2r[3], h2b, sv[3] + bias2r[3]);
      float i2 = sig_s(s0), f2 = sig_s(s1), g2 = tanh_s(s2), o2 = sig_s(s3);
      c2b = fmaf(f2, c2b, i2 * g2);
      h2b = o2 * tanh_s(2.f * LOG2E * c2b);
      if (t >= TT && wv == 0 && lane < BPB)
        out[(size_t)(bbase + lane) * FUTS + (t - TT)] = c2b;
      // next step's LSTM1 input
      if (t + 1 < TT)
        xreg = x_stage[((t + 1) >> 5) & 1][(t + 1) & 31][b];
      else
        xreg = c2b;
    }
  }
}

extern "C" void kernel_launch(void* const* d_in, const int* in_sizes, int n_in,
                              void* d_out, int out_size, void* d_ws, size_t ws_size,
                              hipStream_t stream) {
  const float* input = (const float*)d_in[0];
  const float* W_ih1 = (const float*)d_in[1];
  const float* W_hh1 = (const float*)d_in[2];
  const float* b_ih1 = (const float*)d_in[3];
  const float* b_hh1 = (const float*)d_in[4];
  const float* W_ih2 = (const float*)d_in[5];
  const float* W_hh2 = (const float*)d_in[6];
  const float* b_ih2 = (const float*)d_in[7];
  const float* b_hh2 = (const float*)d_in[8];
  float* out = (float*)d_out;

  lstm_mfma4<<<dim3(BATCH / BPB), dim3(THREADS), 0, stream>>>(
      input, W_ih1, W_hh1, b_ih1, b_hh1, W_ih2, W_hh2, b_ih2, b_hh2, out);
}

// Round 6
// 1099.282 us; speedup vs baseline: 1.1445x; 1.1445x over previous
//
#include <hip/hip_runtime.h>

// TsRnn round 6: force A-fragment register residency (the R3/R4 counters
// proved the compiler was re-staging W_hh1 from global/scratch EVERY step:
// VGPR_Count=128 < A-fragment footprint, FETCH 9-12 GB/dispatch).
//  - run_loop<NT> templated per wave (exactly-sized A arrays, 3 or 4 tiles)
//  - asm "+v" keep-alives on A-fragments + tables: remat impossible
//  - single acc group (16 regs), tables as f32x4 (48), budget ~242 < 256
//  - proven R4 data path: separate h_hi/h_lo planes, 3-product bf16 MFMA,
//    distributed LSTM2 partials + all-wave redundant finish (replicated c2),
//    per-wave part slots (no atomics), ONE barrier per step everywhere.

#define TT      512
#define BATCH   4096
#define CELLN   100
#define FUTS    64
#define THREADS 512
#define BPB     16
#define HPITCH  136   // u16 per h-plane row (272 B, 16B-aligned rows)
#define LOG2E   1.4426950408889634f

typedef __attribute__((ext_vector_type(8))) short bf16x8;
typedef __attribute__((ext_vector_type(4))) float f32x4;

__device__ __forceinline__ unsigned short f2bf(float f) {
  unsigned u = __builtin_bit_cast(unsigned, f);
  return (unsigned short)((u + 0x7FFFu + ((u >> 16) & 1u)) >> 16);
}
__device__ __forceinline__ float bf2f(unsigned short b) {
  return __builtin_bit_cast(float, ((unsigned)b) << 16);
}
// s = x*log2e -> sigmoid(x); safe at +-inf
__device__ __forceinline__ float sig_s(float s) {
  return __builtin_amdgcn_rcpf(1.f + __builtin_amdgcn_exp2f(-s));
}
// u = 2*log2e*x -> tanh(x); safe at +-inf
__device__ __forceinline__ float tanh_s(float u) {
  return fmaf(-2.f, __builtin_amdgcn_rcpf(__builtin_amdgcn_exp2f(u) + 1.f), 1.f);
}
// opaque pass-through: forbids rematerialization of staged fragments
__device__ __forceinline__ void keepv(bf16x8 &v) { asm volatile("" : "+v"(v)); }
__device__ __forceinline__ void keepf(f32x4 &v) { asm volatile("" : "+v"(v)); }

template <int NT>
__device__ __forceinline__ void run_loop(
    int wv, int lane, int b, int q, int mstart, int bbase,
    const float* __restrict__ input, const float* __restrict__ W_ih1,
    const float* __restrict__ W_hh1, const float* __restrict__ b_ih1,
    const float* __restrict__ b_hh1, const float* __restrict__ W_ih2,
    const float* __restrict__ W_hh2, const float* __restrict__ b_ih2,
    const float* __restrict__ b_hh2, float* __restrict__ out,
    unsigned short (*h_hi)[BPB][HPITCH], unsigned short (*h_lo)[BPB][HPITCH],
    float (*part)[8][BPB][4])
{
  // ---- one-time staging: A-fragments (hi/lo bf16) + per-tile tables ----
  // A row permuted R = 4*cell + gate; lane holds A[16m + b][k = 32kk + q*8 + e]
  bf16x8 Ahi[NT][4], Alo[NT][4];
  f32x4 bias4[NT], wx4[NT], w24[NT];
  #pragma unroll
  for (int i = 0; i < NT; ++i) {
    const int m  = mstart + i;
    const int R  = 16 * m + b;
    const int ce = R >> 2, g = R & 3;
    const float sc = (g == 2) ? 2.f * LOG2E : LOG2E;
    #pragma unroll
    for (int kk = 0; kk < 4; ++kk) {
      #pragma unroll
      for (int e = 0; e < 8; ++e) {
        int k = 32 * kk + q * 8 + e;
        float v = (k < CELLN) ? W_hh1[(g * CELLN + ce) * CELLN + k] * sc : 0.f;
        unsigned short vh = f2bf(v);
        Ahi[i][kk][e] = (short)vh;
        Alo[i][kk][e] = (short)f2bf(v - bf2f(vh));
      }
    }
    const int cc = 4 * m + q;
    #pragma unroll
    for (int r = 0; r < 4; ++r) {
      const float scr = (r == 2) ? 2.f * LOG2E : LOG2E;
      bias4[i][r] = (b_ih1[r * CELLN + cc] + b_hh1[r * CELLN + cc]) * scr;
      wx4[i][r]   = W_ih1[r * CELLN + cc] * scr;
      w24[i][r]   = W_ih2[r * CELLN + cc] * scr;
    }
    #pragma unroll
    for (int kk = 0; kk < 4; ++kk) { keepv(Ahi[i][kk]); keepv(Alo[i][kk]); }
    keepf(bias4[i]); keepf(wx4[i]); keepf(w24[i]);
  }

  f32x4 bias2v, whh2v;
  #pragma unroll
  for (int g = 0; g < 4; ++g) {
    const float scg = (g == 2) ? 2.f * LOG2E : LOG2E;
    bias2v[g] = (b_ih2[g] + b_hh2[g]) * scg;
    whh2v[g]  = W_hh2[g] * scg;
  }

  float c1[NT];
  #pragma unroll
  for (int i = 0; i < NT; ++i) c1[i] = 0.f;
  float c2b = 0.f, h2b = 0.f;              // replicated per-lane (batch = b)
  bf16x8 Bhi[4], Blo[4];
  #pragma unroll
  for (int kk = 0; kk < 4; ++kk)
    #pragma unroll
    for (int e = 0; e < 8; ++e) { Bhi[kk][e] = 0; Blo[kk][e] = 0; }
  float xreg  = input[bbase + b];
  float xnext = 0.f;

  // ---------------- time loop: ONE barrier per step ----------------
  for (int t = 0; t < TT + FUTS; ++t) {
    const int p = t & 1;
    if (t + 1 < TT) xnext = input[(size_t)(t + 1) * BATCH + bbase + b];

    // gates = bias + W_ih1*x + W_hh1*h  (3-product bf16 hi/lo emulation)
    f32x4 acc[NT];
    #pragma unroll
    for (int i = 0; i < NT; ++i) acc[i] = wx4[i] * xreg + bias4[i];
    #pragma unroll
    for (int kk = 0; kk < 4; ++kk)
      #pragma unroll
      for (int i = 0; i < NT; ++i)
        acc[i] = __builtin_amdgcn_mfma_f32_16x16x32_bf16(Ahi[i][kk], Bhi[kk], acc[i], 0, 0, 0);
    #pragma unroll
    for (int kk = 0; kk < 4; ++kk)
      #pragma unroll
      for (int i = 0; i < NT; ++i)
        acc[i] = __builtin_amdgcn_mfma_f32_16x16x32_bf16(Alo[i][kk], Bhi[kk], acc[i], 0, 0, 0);
    #pragma unroll
    for (int kk = 0; kk < 4; ++kk)
      #pragma unroll
      for (int i = 0; i < NT; ++i)
        acc[i] = __builtin_amdgcn_mfma_f32_16x16x32_bf16(Ahi[i][kk], Blo[kk], acc[i], 0, 0, 0);

    // activations in-register (reg r = gate r of cell 4m+q, batch b)
    f32x4 pgv = {0.f, 0.f, 0.f, 0.f};
    #pragma unroll
    for (int i = 0; i < NT; ++i) {
      float ig = sig_s(acc[i][0]);
      float fg = sig_s(acc[i][1]);
      float gg = tanh_s(acc[i][2]);
      float og = sig_s(acc[i][3]);
      float cn = fmaf(fg, c1[i], ig * gg);
      c1[i] = cn;
      float hn = og * tanh_s(2.f * LOG2E * cn);
      unsigned short hh = f2bf(hn);
      const int cc = 4 * (mstart + i) + q;
      h_hi[p][b][cc] = hh;
      h_lo[p][b][cc] = f2bf(hn - bf2f(hh));
      pgv += w24[i] * cn;                  // LSTM2 partial (my cells, 4 gates)
    }
    // reduce partials over the 4 q-groups sharing batch b; write wave slot
    #pragma unroll
    for (int g = 0; g < 4; ++g) {
      pgv[g] += __shfl_xor(pgv[g], 16);
      pgv[g] += __shfl_xor(pgv[g], 32);
    }
    {
      float val = (q == 0) ? pgv[0] : (q == 1) ? pgv[1] : (q == 2) ? pgv[2] : pgv[3];
      part[p][wv][b][q] = val;
    }

    __syncthreads();                       // h(t), part(t) published

    // B-build for step t+1 (plane p; step t+1 publishes to p^1)
    const int koff = q * 8;
    #pragma unroll
    for (int kk = 0; kk < 4; ++kk)
      Bhi[kk] = *(const bf16x8*)&h_hi[p][b][kk * 32 + koff];
    #pragma unroll
    for (int kk = 0; kk < 4; ++kk)
      Blo[kk] = *(const bf16x8*)&h_lo[p][b][kk * 32 + koff];

    // LSTM2 finish — every wave redundantly (replicated c2/h2 per lane)
    {
      f32x4 sv = bias2v + whh2v * h2b;
      #pragma unroll
      for (int w2 = 0; w2 < 8; ++w2) sv += *(const f32x4*)&part[p][w2][b][0];
      float i2 = sig_s(sv[0]), f2 = sig_s(sv[1]), g2 = tanh_s(sv[2]), o2 = sig_s(sv[3]);
      c2b = fmaf(f2, c2b, i2 * g2);
      h2b = o2 * tanh_s(2.f * LOG2E * c2b);
      if (t >= TT && wv == 0 && lane < BPB)
        out[(size_t)(bbase + lane) * FUTS + (t - TT)] = c2b;
      xreg = (t + 1 < TT) ? xnext : c2b;   // future phase: x = c2 (replicated)
    }
  }
}

__global__ __launch_bounds__(THREADS, 2) void lstm_mfma6(
    const float* __restrict__ input,
    const float* __restrict__ W_ih1, const float* __restrict__ W_hh1,
    const float* __restrict__ b_ih1, const float* __restrict__ b_hh1,
    const float* __restrict__ W_ih2, const float* __restrict__ W_hh2,
    const float* __restrict__ b_ih2, const float* __restrict__ b_hh2,
    float* __restrict__ out)
{
  __shared__ __align__(16) unsigned short h_hi[2][BPB][HPITCH];
  __shared__ __align__(16) unsigned short h_lo[2][BPB][HPITCH];
  __shared__ __align__(16) float part[2][8][BPB][4];

  const int tid   = threadIdx.x;
  const int lane  = tid & 63;
  const int wv    = tid >> 6;              // wave 0..7
  const int b     = lane & 15;
  const int q     = lane >> 4;
  const int bbase = blockIdx.x * BPB;

  // zero h planes (B-build reads the k=100..127 pad tail)
  for (int e = tid; e < 2 * BPB * HPITCH; e += THREADS) {
    (&h_hi[0][0][0])[e] = 0;
    (&h_lo[0][0][0])[e] = 0;
  }
  __syncthreads();

  // tiles: wave0 -> m 0..3 (NT=4); wave wv -> m 3wv+1..3wv+3 (NT=3); 25 total
  if (wv == 0)
    run_loop<4>(wv, lane, b, q, 0, bbase, input, W_ih1, W_hh1, b_ih1, b_hh1,
                W_ih2, W_hh2, b_ih2, b_hh2, out, h_hi, h_lo, part);
  else
    run_loop<3>(wv, lane, b, q, 3 * wv + 1, bbase, input, W_ih1, W_hh1, b_ih1,
                b_hh1, W_ih2, W_hh2, b_ih2, b_hh2, out, h_hi, h_lo, part);
}

extern "C" void kernel_launch(void* const* d_in, const int* in_sizes, int n_in,
                              void* d_out, int out_size, void* d_ws, size_t ws_size,
                              hipStream_t stream) {
  const float* input = (const float*)d_in[0];
  const float* W_ih1 = (const float*)d_in[1];
  const float* W_hh1 = (const float*)d_in[2];
  const float* b_ih1 = (const float*)d_in[3];
  const float* b_hh1 = (const float*)d_in[4];
  const float* W_ih2 = (const float*)d_in[5];
  const float* W_hh2 = (const float*)d_in[6];
  const float* b_ih2 = (const float*)d_in[7];
  const float* b_hh2 = (const float*)d_in[8];
  float* out = (float*)d_out;

  lstm_mfma6<<<dim3(BATCH / BPB), dim3(THREADS), 0, stream>>>(
      input, W_ih1, W_hh1, b_ih1, b_hh1, W_ih2, W_hh2, b_ih2, b_hh2, out);
}

// Round 7
// 870.038 us; speedup vs baseline: 1.4460x; 1.2635x over previous
//
#include <hip/hip_runtime.h>

// TsRnn round 7: shuffle-free step + augmented-B MFMA.
//  - All __shfl_* removed (they lower to ds_bpermute: the 5.5e7 bank-conflict
//    counter ≈ 372 cy/block-step + serial latency on every wave's path).
//    LSTM2 partials written unreduced (f32x4 per (wave,q,b)); wave 7 owns 0
//    tiles and is the finisher in the observed phase; all waves finish
//    redundantly in the future phase (state handoff via LDS at t=TT-1).
//  - Aug-B slice: x(hi/lo), bias(hi/lo), h[96..99] folded into a 4th K=32
//    MFMA slice -> B-build drops from 8 to 6 b128 reads, no acc-init VALU,
//    same MFMA count (12/tile: accP chain 4, accQ chain 8).
//  - ONE barrier per step in both phases. Tiles {4,4,4,4,3,3,3,0}.

#define TT      512
#define BATCH   4096
#define CELLN   100
#define FUTS    64
#define THREADS 512
#define BPB     16
#define HPITCH  104   // u16 per h-plane row (208 B = 13*16: conflict-free octets)
#define LOG2E   1.4426950408889634f

typedef __attribute__((ext_vector_type(8))) short bf16x8;
typedef __attribute__((ext_vector_type(4))) float f32x4;

__device__ __forceinline__ unsigned short f2bf(float f) {
  unsigned u = __builtin_bit_cast(unsigned, f);
  return (unsigned short)((u + 0x7FFFu + ((u >> 16) & 1u)) >> 16);
}
__device__ __forceinline__ float bf2f(unsigned short b) {
  return __builtin_bit_cast(float, ((unsigned)b) << 16);
}
// s = x*log2e -> sigmoid(x); safe at +-inf
__device__ __forceinline__ float sig_s(float s) {
  return __builtin_amdgcn_rcpf(1.f + __builtin_amdgcn_exp2f(-s));
}
// u = 2*log2e*x -> tanh(x); safe at +-inf
__device__ __forceinline__ float tanh_s(float u) {
  return fmaf(-2.f, __builtin_amdgcn_rcpf(__builtin_amdgcn_exp2f(u) + 1.f), 1.f);
}

template <int NT>
__device__ __forceinline__ void run_loop(
    int wv, int lane, int b, int q, int mstart, int bbase,
    const float* __restrict__ input, const float* __restrict__ W_ih1,
    const float* __restrict__ W_hh1, const float* __restrict__ b_ih1,
    const float* __restrict__ b_hh1, const float* __restrict__ W_ih2,
    const float* __restrict__ W_hh2, const float* __restrict__ b_ih2,
    const float* __restrict__ b_hh2, float* __restrict__ out,
    unsigned short (*h_hi)[BPB][HPITCH], unsigned short (*h_lo)[BPB][HPITCH],
    float (*part)[7][4][BPB][4], float (*hand)[BPB])
{
  constexpr int NTA = (NT > 0) ? NT : 1;

  // ---- one-time staging: A-fragments (kk=0..2 + aug slice) ----
  // A row R = 4*cell + gate = 16m + b; lane holds A[R][k = 32kk + 8q + e].
  // aug slice (idx 3), q==0 lanes: k'=0: W_ih1, k'=1: bias, k'=2..5: W_hh1 tail.
  bf16x8 Ahi[NTA][4], Alo[NTA][4];
  f32x4 w24[NTA];
  float c1[NTA];
  #pragma unroll
  for (int i = 0; i < NT; ++i) {
    const int m  = mstart + i;
    const int R  = 16 * m + b;
    const int ce = R >> 2, g = R & 3;
    const float sc = (g == 2) ? 2.f * LOG2E : LOG2E;
    #pragma unroll
    for (int kk = 0; kk < 3; ++kk) {
      #pragma unroll
      for (int e = 0; e < 8; ++e) {
        int k = 32 * kk + 8 * q + e;               // < 96 always
        float v = W_hh1[(g * CELLN + ce) * CELLN + k] * sc;
        unsigned short vh = f2bf(v);
        Ahi[i][kk][e] = (short)vh;
        Alo[i][kk][e] = (short)f2bf(v - bf2f(vh));
      }
    }
    #pragma unroll
    for (int e = 0; e < 8; ++e) { Ahi[i][3][e] = 0; Alo[i][3][e] = 0; }
    if (q == 0) {
      float av[8];
      av[0] = W_ih1[g * CELLN + ce] * sc;
      av[1] = (b_ih1[g * CELLN + ce] + b_hh1[g * CELLN + ce]) * sc;
      #pragma unroll
      for (int e = 2; e < 6; ++e)
        av[e] = W_hh1[(g * CELLN + ce) * CELLN + 96 + (e - 2)] * sc;
      av[6] = 0.f; av[7] = 0.f;
      #pragma unroll
      for (int e = 0; e < 8; ++e) {
        unsigned short vh = f2bf(av[e]);
        Ahi[i][3][e] = (short)vh;
        Alo[i][3][e] = (short)f2bf(av[e] - bf2f(vh));
      }
    }
    const int cc = 4 * m + q;                       // my C-layout cell
    #pragma unroll
    for (int r = 0; r < 4; ++r) {
      const float scr = (r == 2) ? 2.f * LOG2E : LOG2E;
      w24[i][r] = W_ih2[r * CELLN + cc] * scr;
    }
    c1[i] = 0.f;
  }
  f32x4 bias2v, whh2v;
  #pragma unroll
  for (int g = 0; g < 4; ++g) {
    const float scg = (g == 2) ? 2.f * LOG2E : LOG2E;
    bias2v[g] = (b_ih2[g] + b_hh2[g]) * scg;
    whh2v[g]  = W_hh2[g] * scg;
  }

  float c2b = 0.f, h2b = 0.f;                       // per-lane, batch = b
  float xreg = (NT > 0) ? input[bbase + b] : 0.f;

  // ---------------- time loop: ONE barrier per body ----------------
  for (int t = 0; t <= TT + FUTS; ++t) {
    const int p = t & 1, pp = p ^ 1;
    const bool fut = (t >= TT);

    // ---- LSTM2 finish(t-1): wave 7 always (t>=1); all waves when fut ----
    if ((NT == 0) ? (t >= 1) : fut) {
      if (NT > 0 && t == TT) { c2b = hand[0][b]; h2b = hand[1][b]; }
      f32x4 s0 = *(const f32x4*)&part[pp][0][0][b][0];
      f32x4 s1 = *(const f32x4*)&part[pp][0][1][b][0];
      f32x4 s2 = *(const f32x4*)&part[pp][0][2][b][0];
      f32x4 s3 = *(const f32x4*)&part[pp][0][3][b][0];
      #pragma unroll
      for (int w2 = 1; w2 < 7; ++w2) {
        s0 += *(const f32x4*)&part[pp][w2][0][b][0];
        s1 += *(const f32x4*)&part[pp][w2][1][b][0];
        s2 += *(const f32x4*)&part[pp][w2][2][b][0];
        s3 += *(const f32x4*)&part[pp][w2][3][b][0];
      }
      f32x4 sv = ((s0 + s1) + (s2 + s3)) + bias2v + whh2v * h2b;
      float i2 = sig_s(sv[0]), f2 = sig_s(sv[1]);
      float g2 = tanh_s(sv[2]), o2 = sig_s(sv[3]);
      c2b = fmaf(f2, c2b, i2 * g2);
      h2b = o2 * tanh_s(2.f * LOG2E * c2b);
      if (fut) {
        if (t > TT && wv == 0 && q == 0)
          out[(size_t)(bbase + b) * FUTS + (t - 1 - TT)] = c2b;
        xreg = c2b;                                  // next LSTM1 input
      }
    }

    // ---- main LSTM1 step t ----
    if (NT > 0 && t < TT + FUTS) {
      float xn = 0.f;
      if (t + 1 < TT) xn = input[(size_t)(t + 1) * BATCH + bbase + b];

      // B-build from planes parity pp (h(t-1)); aug from xreg + tail
      bf16x8 Bh[3], Bl[3];
      #pragma unroll
      for (int kk = 0; kk < 3; ++kk) {
        Bh[kk] = *(const bf16x8*)&h_hi[pp][b][kk * 32 + 8 * q];
        Bl[kk] = *(const bf16x8*)&h_lo[pp][b][kk * 32 + 8 * q];
      }
      bf16x8 aBh, aBl;
      #pragma unroll
      for (int e = 0; e < 8; ++e) { aBh[e] = 0; aBl[e] = 0; }
      if (q == 0) {
        unsigned short xh = f2bf(xreg);
        unsigned short xl = f2bf(xreg - bf2f(xh));
        aBh[0] = (short)xh; aBh[1] = (short)0x3F80;  // bf16(1.0)
        aBl[0] = (short)xl;
        #pragma unroll
        for (int e = 0; e < 4; ++e) {
          aBh[2 + e] = (short)h_hi[pp][b][96 + e];
          aBl[2 + e] = (short)h_lo[pp][b][96 + e];
        }
      }

      f32x4 accP[NTA], accQ[NTA];
      #pragma unroll
      for (int i = 0; i < NT; ++i) {
        accP[i] = f32x4{0.f, 0.f, 0.f, 0.f};
        accQ[i] = f32x4{0.f, 0.f, 0.f, 0.f};
      }
      #pragma unroll
      for (int kk = 0; kk < 3; ++kk)
        #pragma unroll
        for (int i = 0; i < NT; ++i)
          accP[i] = __builtin_amdgcn_mfma_f32_16x16x32_bf16(Ahi[i][kk], Bh[kk], accP[i], 0, 0, 0);
      #pragma unroll
      for (int i = 0; i < NT; ++i)
        accP[i] = __builtin_amdgcn_mfma_f32_16x16x32_bf16(Ahi[i][3], aBh, accP[i], 0, 0, 0);
      #pragma unroll
      for (int kk = 0; kk < 3; ++kk)
        #pragma unroll
        for (int i = 0; i < NT; ++i)
          accQ[i] = __builtin_amdgcn_mfma_f32_16x16x32_bf16(Alo[i][kk], Bh[kk], accQ[i], 0, 0, 0);
      #pragma unroll
      for (int i = 0; i < NT; ++i)
        accQ[i] = __builtin_amdgcn_mfma_f32_16x16x32_bf16(Alo[i][3], aBh, accQ[i], 0, 0, 0);
      #pragma unroll
      for (int kk = 0; kk < 3; ++kk)
        #pragma unroll
        for (int i = 0; i < NT; ++i)
          accQ[i] = __builtin_amdgcn_mfma_f32_16x16x32_bf16(Ahi[i][kk], Bl[kk], accQ[i], 0, 0, 0);
      #pragma unroll
      for (int i = 0; i < NT; ++i)
        accQ[i] = __builtin_amdgcn_mfma_f32_16x16x32_bf16(Ahi[i][3], aBl, accQ[i], 0, 0, 0);

      // activations (reg r = gate r of cell 4m+q, batch b) + publish + pgv
      f32x4 pgv = {0.f, 0.f, 0.f, 0.f};
      #pragma unroll
      for (int i = 0; i < NT; ++i) {
        float si = accP[i][0] + accQ[i][0];
        float sf = accP[i][1] + accQ[i][1];
        float sg = accP[i][2] + accQ[i][2];
        float so = accP[i][3] + accQ[i][3];
        float ig = sig_s(si), fg = sig_s(sf), gg = tanh_s(sg), og = sig_s(so);
        float cn = fmaf(fg, c1[i], ig * gg);
        c1[i] = cn;
        float hn = og * tanh_s(2.f * LOG2E * cn);
        unsigned short hh = f2bf(hn);
        const int cc = 4 * (mstart + i) + q;
        h_hi[p][b][cc] = hh;
        h_lo[p][b][cc] = f2bf(hn - bf2f(hh));
        pgv += w24[i] * cn;
      }
      *(f32x4*)&part[p][wv][q][b][0] = pgv;          // unreduced: no shuffles

      if (t + 1 < TT) xreg = xn;
    }

    // state handoff for the all-wave future finish
    if (NT == 0 && t == TT - 1 && q == 0) { hand[0][b] = c2b; hand[1][b] = h2b; }

    __syncthreads();
  }
}

__global__ __launch_bounds__(THREADS, 2) void lstm_mfma7(
    const float* __restrict__ input,
    const float* __restrict__ W_ih1, const float* __restrict__ W_hh1,
    const float* __restrict__ b_ih1, const float* __restrict__ b_hh1,
    const float* __restrict__ W_ih2, const float* __restrict__ W_hh2,
    const float* __restrict__ b_ih2, const float* __restrict__ b_hh2,
    float* __restrict__ out)
{
  __shared__ __align__(16) unsigned short h_hi[2][BPB][HPITCH];
  __shared__ __align__(16) unsigned short h_lo[2][BPB][HPITCH];
  __shared__ __align__(16) float part[2][7][4][BPB][4];
  __shared__ __align__(16) float hand[2][BPB];

  const int tid   = threadIdx.x;
  const int lane  = tid & 63;
  const int wv    = tid >> 6;                 // wave 0..7
  const int b     = lane & 15;
  const int q     = lane >> 4;
  const int bbase = blockIdx.x * BPB;

  // zero both plane parities (body 0 reads parity 1)
  for (int e = tid; e < 2 * BPB * HPITCH; e += THREADS) {
    (&h_hi[0][0][0])[e] = 0;
    (&h_lo[0][0][0])[e] = 0;
  }
  __syncthreads();

  // tiles {4,4,4,4,3,3,3,0}: wv<4 -> m=4wv..; wv 4..6 -> m=16+3(wv-4)..; wv7 finisher
  if (wv < 4)
    run_loop<4>(wv, lane, b, q, 4 * wv, bbase, input, W_ih1, W_hh1, b_ih1,
                b_hh1, W_ih2, W_hh2, b_ih2, b_hh2, out, h_hi, h_lo, part, hand);
  else if (wv < 7)
    run_loop<3>(wv, lane, b, q, 16 + 3 * (wv - 4), bbase, input, W_ih1, W_hh1,
                b_ih1, b_hh1, W_ih2, W_hh2, b_ih2, b_hh2, out, h_hi, h_lo, part, hand);
  else
    run_loop<0>(wv, lane, b, q, 0, bbase, input, W_ih1, W_hh1, b_ih1, b_hh1,
                W_ih2, W_hh2, b_ih2, b_hh2, out, h_hi, h_lo, part, hand);
}

extern "C" void kernel_launch(void* const* d_in, const int* in_sizes, int n_in,
                              void* d_out, int out_size, void* d_ws, size_t ws_size,
                              hipStream_t stream) {
  const float* input = (const float*)d_in[0];
  const float* W_ih1 = (const float*)d_in[1];
  const float* W_hh1 = (const float*)d_in[2];
  const float* b_ih1 = (const float*)d_in[3];
  const float* b_hh1 = (const float*)d_in[4];
  const float* W_ih2 = (const float*)d_in[5];
  const float* W_hh2 = (const float*)d_in[6];
  const float* b_ih2 = (const float*)d_in[7];
  const float* b_hh2 = (const float*)d_in[8];
  float* out = (float*)d_out;

  lstm_mfma7<<<dim3(BATCH / BPB), dim3(THREADS), 0, stream>>>(
      input, W_ih1, W_hh1, b_ih1, b_hh1, W_ih2, W_hh2, b_ih2, b_hh2, out);
}

// Round 8
// 662.015 us; speedup vs baseline: 1.9004x; 1.3142x over previous
//
#include <hip/hip_runtime.h>

// TsRnn round 8: 2-product MFMA emulation (W = bf16 hi+lo, h = single bf16).
//  Rationale: absmax = 2^-11 in EVERY passing round incl. pure-fp32 R1 ->
//  reference-side fp32 drift dominates; the 3rd (h-lo) product was buying
//  nothing measurable. Dropping it: MFMA 48->32 per wave-step, h_lo plane
//  (stores, residual math, 3 b128 reads) deleted, single 8-deep acc chain.
//  Aug slice keeps x and bias at ~2^-17: B-aug=[x_hi,x_lo,1,h96..99,0],
//  Ahi-aug=[Wih_hi,Wih_hi,bias_hi,Wt_hi..], Alo-aug=[Wih_lo,0,bias_lo,Wt_lo..].
//  Otherwise R7 structure: shuffle-free, one barrier/body, wave-7 finisher
//  (observed) / all-wave redundant finish (future), tiles {4,4,4,4,3,3,3,0}.

#define TT      512
#define BATCH   4096
#define CELLN   100
#define FUTS    64
#define THREADS 512
#define BPB     16
#define HPITCH  104   // u16 per h-plane row (208 B = 13*16: conflict-free octets)
#define LOG2E   1.4426950408889634f

typedef __attribute__((ext_vector_type(8))) short bf16x8;
typedef __attribute__((ext_vector_type(4))) float f32x4;
typedef __attribute__((ext_vector_type(4))) unsigned short u16x4;

__device__ __forceinline__ unsigned short f2bf(float f) {
  unsigned u = __builtin_bit_cast(unsigned, f);
  return (unsigned short)((u + 0x7FFFu + ((u >> 16) & 1u)) >> 16);
}
__device__ __forceinline__ float bf2f(unsigned short b) {
  return __builtin_bit_cast(float, ((unsigned)b) << 16);
}
// s = x*log2e -> sigmoid(x); safe at +-inf
__device__ __forceinline__ float sig_s(float s) {
  return __builtin_amdgcn_rcpf(1.f + __builtin_amdgcn_exp2f(-s));
}
// u = 2*log2e*x -> tanh(x); safe at +-inf
__device__ __forceinline__ float tanh_s(float u) {
  return fmaf(-2.f, __builtin_amdgcn_rcpf(__builtin_amdgcn_exp2f(u) + 1.f), 1.f);
}

template <int NT>
__device__ __forceinline__ void run_loop(
    int wv, int lane, int b, int q, int mstart, int bbase,
    const float* __restrict__ input, const float* __restrict__ W_ih1,
    const float* __restrict__ W_hh1, const float* __restrict__ b_ih1,
    const float* __restrict__ b_hh1, const float* __restrict__ W_ih2,
    const float* __restrict__ W_hh2, const float* __restrict__ b_ih2,
    const float* __restrict__ b_hh2, float* __restrict__ out,
    unsigned short (*h_hi)[BPB][HPITCH],
    float (*part)[7][4][BPB][4], float (*hand)[BPB])
{
  constexpr int NTA = (NT > 0) ? NT : 1;

  // ---- one-time staging: A-fragments (W hi+lo; kk=0..2 + aug slice) ----
  // A row R = 4*cell + gate = 16m + b; lane holds A[R][k = 32kk + 8q + e].
  bf16x8 Ahi[NTA][4], Alo[NTA][4];
  f32x4 w24[NTA];
  float c1[NTA];
  #pragma unroll
  for (int i = 0; i < NT; ++i) {
    const int m  = mstart + i;
    const int R  = 16 * m + b;
    const int ce = R >> 2, g = R & 3;
    const float sc = (g == 2) ? 2.f * LOG2E : LOG2E;
    #pragma unroll
    for (int kk = 0; kk < 3; ++kk) {
      #pragma unroll
      for (int e = 0; e < 8; ++e) {
        int k = 32 * kk + 8 * q + e;               // < 96 always
        float v = W_hh1[(g * CELLN + ce) * CELLN + k] * sc;
        unsigned short vh = f2bf(v);
        Ahi[i][kk][e] = (short)vh;
        Alo[i][kk][e] = (short)f2bf(v - bf2f(vh));
      }
    }
    #pragma unroll
    for (int e = 0; e < 8; ++e) { Ahi[i][3][e] = 0; Alo[i][3][e] = 0; }
    if (q == 0) {
      // aug A: [Wih(*x_hi), Wih_hi(*x_lo), bias(*1), Wtail(*h96..99), 0]
      float wih = W_ih1[g * CELLN + ce] * sc;
      float bia = (b_ih1[g * CELLN + ce] + b_hh1[g * CELLN + ce]) * sc;
      unsigned short wih_h = f2bf(wih);
      unsigned short bia_h = f2bf(bia);
      Ahi[i][3][0] = (short)wih_h;  Alo[i][3][0] = (short)f2bf(wih - bf2f(wih_h));
      Ahi[i][3][1] = (short)wih_h;  Alo[i][3][1] = 0;
      Ahi[i][3][2] = (short)bia_h;  Alo[i][3][2] = (short)f2bf(bia - bf2f(bia_h));
      #pragma unroll
      for (int e = 3; e < 7; ++e) {
        float wt = W_hh1[(g * CELLN + ce) * CELLN + 96 + (e - 3)] * sc;
        unsigned short wt_h = f2bf(wt);
        Ahi[i][3][e] = (short)wt_h;
        Alo[i][3][e] = (short)f2bf(wt - bf2f(wt_h));
      }
    }
    const int cc = 4 * m + q;                       // my C-layout cell
    #pragma unroll
    for (int r = 0; r < 4; ++r) {
      const float scr = (r == 2) ? 2.f * LOG2E : LOG2E;
      w24[i][r] = W_ih2[r * CELLN + cc] * scr;
    }
    c1[i] = 0.f;
  }
  f32x4 bias2v, whh2v;
  #pragma unroll
  for (int g = 0; g < 4; ++g) {
    const float scg = (g == 2) ? 2.f * LOG2E : LOG2E;
    bias2v[g] = (b_ih2[g] + b_hh2[g]) * scg;
    whh2v[g]  = W_hh2[g] * scg;
  }

  float c2b = 0.f, h2b = 0.f;                       // per-lane, batch = b
  float xreg = (NT > 0) ? input[bbase + b] : 0.f;
  const float* xp = input + BATCH + bbase + b;      // marching ptr -> x(t+1)

  // ---------------- time loop: ONE barrier per body ----------------
  for (int t = 0; t <= TT + FUTS; ++t) {
    const int p = t & 1, pp = p ^ 1;
    const bool fut = (t >= TT);

    // ---- LSTM2 finish(t-1): wave 7 always (t>=1); all waves when fut ----
    if ((NT == 0) ? (t >= 1) : fut) {
      if (NT > 0 && t == TT) { c2b = hand[0][b]; h2b = hand[1][b]; }
      f32x4 s0 = *(const f32x4*)&part[pp][0][0][b][0];
      f32x4 s1 = *(const f32x4*)&part[pp][0][1][b][0];
      f32x4 s2 = *(const f32x4*)&part[pp][0][2][b][0];
      f32x4 s3 = *(const f32x4*)&part[pp][0][3][b][0];
      #pragma unroll
      for (int w2 = 1; w2 < 7; ++w2) {
        s0 += *(const f32x4*)&part[pp][w2][0][b][0];
        s1 += *(const f32x4*)&part[pp][w2][1][b][0];
        s2 += *(const f32x4*)&part[pp][w2][2][b][0];
        s3 += *(const f32x4*)&part[pp][w2][3][b][0];
      }
      f32x4 sv = ((s0 + s1) + (s2 + s3)) + bias2v + whh2v * h2b;
      float i2 = sig_s(sv[0]), f2 = sig_s(sv[1]);
      float g2 = tanh_s(sv[2]), o2 = sig_s(sv[3]);
      c2b = fmaf(f2, c2b, i2 * g2);
      h2b = o2 * tanh_s(2.f * LOG2E * c2b);
      if (fut) {
        if (t > TT && wv == 0 && q == 0)
          out[(size_t)(bbase + b) * FUTS + (t - 1 - TT)] = c2b;
        xreg = c2b;                                  // next LSTM1 input
      }
    }

    // ---- main LSTM1 step t ----
    if (NT > 0 && t < TT + FUTS) {
      float xn = 0.f;
      if (t + 1 < TT) { xn = *xp; xp += BATCH; }

      // B-build from plane parity pp (h(t-1)); aug from xreg + h tail
      bf16x8 Bh[3];
      #pragma unroll
      for (int kk = 0; kk < 3; ++kk)
        Bh[kk] = *(const bf16x8*)&h_hi[pp][b][kk * 32 + 8 * q];
      bf16x8 aB;
      #pragma unroll
      for (int e = 0; e < 8; ++e) aB[e] = 0;
      if (q == 0) {
        unsigned short xh = f2bf(xreg);
        unsigned short xl = f2bf(xreg - bf2f(xh));
        aB[0] = (short)xh; aB[1] = (short)xl; aB[2] = (short)0x3F80;  // 1.0
        u16x4 tail = *(const u16x4*)&h_hi[pp][b][96];
        #pragma unroll
        for (int e = 0; e < 4; ++e) aB[3 + e] = (short)tail[e];
      }

      // single acc, 8-deep chain per tile (4 independent chains hide latency)
      f32x4 acc[NTA];
      #pragma unroll
      for (int i = 0; i < NT; ++i) acc[i] = f32x4{0.f, 0.f, 0.f, 0.f};
      #pragma unroll
      for (int kk = 0; kk < 3; ++kk)
        #pragma unroll
        for (int i = 0; i < NT; ++i)
          acc[i] = __builtin_amdgcn_mfma_f32_16x16x32_bf16(Ahi[i][kk], Bh[kk], acc[i], 0, 0, 0);
      #pragma unroll
      for (int i = 0; i < NT; ++i)
        acc[i] = __builtin_amdgcn_mfma_f32_16x16x32_bf16(Ahi[i][3], aB, acc[i], 0, 0, 0);
      #pragma unroll
      for (int kk = 0; kk < 3; ++kk)
        #pragma unroll
        for (int i = 0; i < NT; ++i)
          acc[i] = __builtin_amdgcn_mfma_f32_16x16x32_bf16(Alo[i][kk], Bh[kk], acc[i], 0, 0, 0);
      #pragma unroll
      for (int i = 0; i < NT; ++i)
        acc[i] = __builtin_amdgcn_mfma_f32_16x16x32_bf16(Alo[i][3], aB, acc[i], 0, 0, 0);

      // activations (reg r = gate r of cell 4m+q, batch b) + publish + pgv
      f32x4 pgv = {0.f, 0.f, 0.f, 0.f};
      #pragma unroll
      for (int i = 0; i < NT; ++i) {
        float ig = sig_s(acc[i][0]);
        float fg = sig_s(acc[i][1]);
        float gg = tanh_s(acc[i][2]);
        float og = sig_s(acc[i][3]);
        float cn = fmaf(fg, c1[i], ig * gg);
        c1[i] = cn;
        float hn = og * tanh_s(2.f * LOG2E * cn);
        const int cc = 4 * (mstart + i) + q;
        h_hi[p][b][cc] = f2bf(hn);                   // h -> single bf16 (RTN)
        pgv += w24[i] * cn;
      }
      *(f32x4*)&part[p][wv][q][b][0] = pgv;          // unreduced: no shuffles

      if (t + 1 < TT) xreg = xn;
    }

    // state handoff for the all-wave future finish
    if (NT == 0 && t == TT - 1 && q == 0) { hand[0][b] = c2b; hand[1][b] = h2b; }

    __syncthreads();
  }
}

__global__ __launch_bounds__(THREADS, 2) void lstm_mfma8(
    const float* __restrict__ input,
    const float* __restrict__ W_ih1, const float* __restrict__ W_hh1,
    const float* __restrict__ b_ih1, const float* __restrict__ b_hh1,
    const float* __restrict__ W_ih2, const float* __restrict__ W_hh2,
    const float* __restrict__ b_ih2, const float* __restrict__ b_hh2,
    float* __restrict__ out)
{
  __shared__ __align__(16) unsigned short h_hi[2][BPB][HPITCH];
  __shared__ __align__(16) float part[2][7][4][BPB][4];
  __shared__ __align__(16) float hand[2][BPB];

  const int tid   = threadIdx.x;
  const int lane  = tid & 63;
  const int wv    = tid >> 6;                 // wave 0..7
  const int b     = lane & 15;
  const int q     = lane >> 4;
  const int bbase = blockIdx.x * BPB;

  // zero both plane parities (body 0 reads parity 1; k tail 100..103 stays 0)
  for (int e = tid; e < 2 * BPB * HPITCH; e += THREADS)
    (&h_hi[0][0][0])[e] = 0;
  __syncthreads();

  // tiles {4,4,4,4,3,3,3,0}: wv<4 -> m=4wv..; wv 4..6 -> m=16+3(wv-4)..; wv7 finisher
  if (wv < 4)
    run_loop<4>(wv, lane, b, q, 4 * wv, bbase, input, W_ih1, W_hh1, b_ih1,
                b_hh1, W_ih2, W_hh2, b_ih2, b_hh2, out, h_hi, part, hand);
  else if (wv < 7)
    run_loop<3>(wv, lane, b, q, 16 + 3 * (wv - 4), bbase, input, W_ih1, W_hh1,
                b_ih1, b_hh1, W_ih2, W_hh2, b_ih2, b_hh2, out, h_hi, part, hand);
  else
    run_loop<0>(wv, lane, b, q, 0, bbase, input, W_ih1, W_hh1, b_ih1, b_hh1,
                W_ih2, W_hh2, b_ih2, b_hh2, out, h_hi, part, hand);
}

extern "C" void kernel_launch(void* const* d_in, const int* in_sizes, int n_in,
                              void* d_out, int out_size, void* d_ws, size_t ws_size,
                              hipStream_t stream) {
  const float* input = (const float*)d_in[0];
  const float* W_ih1 = (const float*)d_in[1];
  const float* W_hh1 = (const float*)d_in[2];
  const float* b_ih1 = (const float*)d_in[3];
  const float* b_hh1 = (const float*)d_in[4];
  const float* W_ih2 = (const float*)d_in[5];
  const float* W_hh2 = (const float*)d_in[6];
  const float* b_ih2 = (const float*)d_in[7];
  const float* b_hh2 = (const float*)d_in[8];
  float* out = (float*)d_out;

  lstm_mfma8<<<dim3(BATCH / BPB), dim3(THREADS), 0, stream>>>(
      input, W_ih1, W_hh1, b_ih1, b_hh1, W_ih2, W_hh2, b_ih2, b_hh2, out);
}